// Round 7
// baseline (1295.055 us; speedup 1.0000x reference)
//
#include <hip/hip_runtime.h>
#include <hip/hip_bf16.h>

typedef __hip_bfloat16 bf16;
typedef __attribute__((ext_vector_type(8))) short short8;
typedef __attribute__((ext_vector_type(4))) float f32x4;

#define NN 20000
#define NE 80000
#define DD 128
#define NITER 15
#define HSTRIDE 136   // 272 B row stride: 16B-aligned rows, 2-way LDS aliasing (free)

__device__ inline void gload16(const void* g, void* l) {
  __builtin_amdgcn_global_load_lds(
      (const __attribute__((address_space(1))) void*)g,
      (__attribute__((address_space(3))) void*)l, 16, 0, 0);
}

__device__ inline float bfbits2f(unsigned int hi16) {
  union { unsigned int u; float f; } c; c.u = hi16; return c.f;
}

// ---------------------------------------------------------------------------
// dtype auto-detect. flag = 1 -> bf16 ; flag = 0 -> fp32.
// ---------------------------------------------------------------------------
__global__ void detect_kernel(const unsigned short* __restrict__ p, int nhalf,
                              int* __restrict__ flag) {
  __shared__ int cs[256], ct[256];
  const int t = threadIdx.x;
  int sane = 0, tot = 0;
  for (int i = 2 * t; i < nhalf; i += 512) {
    unsigned short v = p[i];
    int e = (v >> 7) & 0xFF;
    tot++;
    if (v == 0 || (e >= 80 && e <= 170)) sane++;
  }
  cs[t] = sane; ct[t] = tot;
  __syncthreads();
  for (int o = 128; o > 0; o >>= 1) {
    if (t < o) { cs[t] += cs[t + o]; ct[t] += ct[t + o]; }
    __syncthreads();
  }
  if (t == 0) *flag = (cs[0] * 10 > ct[0] * 7) ? 1 : 0;
}

__global__ void in2fb_kernel(const void* __restrict__ src, float* __restrict__ dstf,
                             bf16* __restrict__ dstb, int n, const int* __restrict__ flag) {
  int i = blockIdx.x * 256 + threadIdx.x;
  if (i < n) {
    float v = (*flag) ? (float)((const bf16*)src)[i] : ((const float*)src)[i];
    dstf[i] = v;
    dstb[i] = (bf16)v;
  }
}

__global__ void in2f_kernel(const void* __restrict__ src, float* __restrict__ dst,
                            int n, const int* __restrict__ flag) {
  int i = blockIdx.x * 256 + threadIdx.x;
  if (i < n) {
    dst[i] = (*flag) ? (float)((const bf16*)src)[i] : ((const float*)src)[i];
  }
}

// W [NITER][K][128] -> Wt [NITER][128][K] bf16
__global__ void w2t_kernel(const void* __restrict__ W, bf16* __restrict__ Wt,
                           int K, const int* __restrict__ flag) {
  int i = blockIdx.x * 256 + threadIdx.x;
  int total = NITER * K * DD;
  if (i < total) {
    float v = (*flag) ? (float)((const bf16*)W)[i] : ((const float*)W)[i];
    int t = i / (K * DD);
    int rem = i - t * K * DD;
    int k = rem >> 7;
    int n = rem & 127;
    Wt[(size_t)t * K * DD + (size_t)n * K + k] = (bf16)v;
  }
}

__global__ void outw_kernel(const float* __restrict__ xf, const float* __restrict__ ef,
                            void* __restrict__ out, const int* __restrict__ flag) {
  int i = blockIdx.x * 256 + threadIdx.x;
  const int nx = NN * DD, total = (NN + NE) * DD;
  if (i < total) {
    float v = (i < nx) ? xf[i] : ef[i - nx];
    if (*flag) ((bf16*)out)[i] = (bf16)v;
    else       ((float*)out)[i] = v;
  }
}

// ---------------------------------------------------------------------------
// Fused 3-layer MLP, software-pipelined. 128x128 tile, 4 row-split waves
// (wave = 32 rows x 128 cols, acc 2x8). B staged through DOUBLE-BUFFERED LDS
// via global_load_lds: DMA for slab s+1 issued before computing slab s, so
// the pre-barrier vmcnt drain overlaps compute (1 barrier/slab). Phase-1 A
// gathers prefetched one slab ahead into registers. LayerNorm LDS-free.
// AMODE 1: A0 = concat(xb[row[m]], xb[col[m]], eb[m])  (K0=384)
// AMODE 2: A0 = concat(xb[m], aggb[m])                 (K0=256)
// ---------------------------------------------------------------------------
template<int K0, int AMODE>
__global__ __launch_bounds__(256, 3) void fused_mlp(
    const bf16*  __restrict__ S0b,
    const bf16*  __restrict__ S1b,
    const int*   __restrict__ eidx,
    const bf16*  __restrict__ W0t,   // [128][K0]
    const bf16*  __restrict__ W1t,   // [128][128]
    const bf16*  __restrict__ W2t,   // [128][128]
    const float* __restrict__ b0,
    const float* __restrict__ b1,
    const float* __restrict__ b2,
    const float* __restrict__ gamma,
    const float* __restrict__ beta,
    float*       __restrict__ stf,   // fp32 residual state (in/out)
    bf16*        __restrict__ stb,   // bf16 mirror (out)
    int M)
{
  __shared__ __align__(16) bf16 Bls[2][128 * 32];    // double-buffered W slab
  __shared__ __align__(16) bf16 Hls[128 * HSTRIDE];  // inter-layer activations

  const int tid  = threadIdx.x;
  const int lane = tid & 63;
  const int wv   = tid >> 6;                  // wave's 32-row band
  const int l15  = lane & 15, quad = lane >> 4;
  const int m0   = blockIdx.x * 128;

  const int scol = tid >> 2;                  // DMA: weight col 0..63 (+64)
  const int sk8  = (tid & 3) * 8;             // DMA: 8-elem chunk in slab

  int rowm[2], ir[2], ic[2];
#pragma unroll
  for (int mi = 0; mi < 2; mi++) {
    rowm[mi] = min(m0 + wv * 32 + mi * 16 + l15, M - 1);
    if (AMODE == 1) { ir[mi] = eidx[rowm[mi]]; ic[mi] = eidx[NE + rowm[mi]]; }
  }

  // DMA one 32-K slab of a [128][K] weight into Bls[buf]
  auto dmaW = [&](const bf16* W, int K, int kk, int buf) {
    gload16(W + (size_t)scol * K + kk + sk8,        &Bls[buf][scol * 32 + sk8]);
    gload16(W + (size_t)(scol + 64) * K + kk + sk8, &Bls[buf][(scol + 64) * 32 + sk8]);
  };
  // phase-1 A gather for a 32-K slab into registers
  auto gatherA = [&](int kk, short8 a[2]) {
    const int ks = (kk & 127) + quad * 8;
#pragma unroll
    for (int mi = 0; mi < 2; mi++) {
      const bf16* base;
      if (AMODE == 1) {
        const int seg = kk >> 7;
        base = (seg == 0) ? S0b + (size_t)ir[mi] * DD
             : (seg == 1) ? S0b + (size_t)ic[mi] * DD
                          : S1b + (size_t)rowm[mi] * DD;
      } else {
        base = (kk >> 7) ? S1b + (size_t)rowm[mi] * DD
                         : S0b + (size_t)rowm[mi] * DD;
      }
      a[mi] = *(const short8*)(base + ks);
    }
  };

  f32x4 acc[2][8];
  auto zacc = [&]() {
#pragma unroll
    for (int i = 0; i < 2; i++)
#pragma unroll
      for (int j = 0; j < 8; j++) acc[i][j] = (f32x4){0.f, 0.f, 0.f, 0.f};
  };
  // one slab of MFMAs: A from regs, B from Bls[buf]
  auto slabMfmaA = [&](const short8 a[2], int buf) {
    short8 bfr[8];
#pragma unroll
    for (int ni = 0; ni < 8; ni++)
      bfr[ni] = *(const short8*)&Bls[buf][(ni * 16 + l15) * 32 + quad * 8];
#pragma unroll
    for (int mi = 0; mi < 2; mi++)
#pragma unroll
      for (int ni = 0; ni < 8; ni++)
        acc[mi][ni] = __builtin_amdgcn_mfma_f32_16x16x32_bf16(a[mi], bfr[ni], acc[mi][ni], 0, 0, 0);
  };
  // one slab of MFMAs: A from Hls at k-offset kk, B from Bls[buf]
  auto slabMfmaH = [&](int kk, int buf) {
    short8 a[2], bfr[8];
#pragma unroll
    for (int mi = 0; mi < 2; mi++)
      a[mi] = *(const short8*)&Hls[(wv * 32 + mi * 16 + l15) * HSTRIDE + kk + quad * 8];
#pragma unroll
    for (int ni = 0; ni < 8; ni++)
      bfr[ni] = *(const short8*)&Bls[buf][(ni * 16 + l15) * 32 + quad * 8];
#pragma unroll
    for (int mi = 0; mi < 2; mi++)
#pragma unroll
      for (int ni = 0; ni < 8; ni++)
        acc[mi][ni] = __builtin_amdgcn_mfma_f32_16x16x32_bf16(a[mi], bfr[ni], acc[mi][ni], 0, 0, 0);
  };
  // relu(acc + bias) -> Hls (wave's own 32-row band)
  auto writeH = [&](const float* bias) {
    float bv[8];
#pragma unroll
    for (int ni = 0; ni < 8; ni++) bv[ni] = bias[ni * 16 + l15];
#pragma unroll
    for (int mi = 0; mi < 2; mi++)
#pragma unroll
      for (int r = 0; r < 4; r++) {
        const int row = wv * 32 + mi * 16 + quad * 4 + r;
#pragma unroll
        for (int ni = 0; ni < 8; ni++)
          Hls[row * HSTRIDE + ni * 16 + l15] = (bf16)fmaxf(acc[mi][ni][r] + bv[ni], 0.f);
      }
  };

  constexpr int NS1 = K0 / 32;      // phase-1 slabs (12 or 8); even

  // ---------------- Phase 1: H0 = relu(A0 @ W0 + b0) ----------------
  zacc();
  short8 aCur[2], aNxt[2];
  dmaW(W0t, K0, 0, 0);
  gatherA(0, aCur);
  __syncthreads();                                   // slab 0 B + A ready
#pragma unroll
  for (int s = 0; s < NS1; s++) {
    if (s + 1 < NS1) {
      dmaW(W0t, K0, (s + 1) * 32, (s + 1) & 1);      // in flight during compute
      gatherA((s + 1) * 32, aNxt);
    } else {
      dmaW(W1t, 128, 0, NS1 & 1);                    // prefetch phase-2 slab 0
    }
    slabMfmaA(aCur, s & 1);
    __syncthreads();                                 // drains DMA(s+1)
    aCur[0] = aNxt[0]; aCur[1] = aNxt[1];
  }
  writeH(b0);
  __syncthreads();                                   // H0 visible (fence)

  // ---------------- Phase 2: H1 = relu(H0 @ W1 + b1) ----------------
  zacc();
#pragma unroll
  for (int s = 0; s < 4; s++) {
    if (s < 3) dmaW(W1t, 128, (s + 1) * 32, (NS1 + s + 1) & 1);
    else       dmaW(W2t, 128, 0,            (NS1 + 4) & 1);   // prefetch phase-3
    slabMfmaH(s * 32, (NS1 + s) & 1);
    __syncthreads();
  }
  writeH(b1);
  __syncthreads();

  // ---------------- Phase 3: Y = H1 @ W2 + b2 ; LN ; residual ----------------
  zacc();
#pragma unroll
  for (int s = 0; s < 4; s++) {
    if (s < 3) dmaW(W2t, 128, (s + 1) * 32, (NS1 + 4 + s + 1) & 1);
    slabMfmaH(s * 32, (NS1 + 4 + s) & 1);
    if (s < 3) __syncthreads();
  }

  // LN: full row within wave -> in-lane ni-sum + 16-lane butterfly. No LDS.
  float bv[8], gv[8], btv[8];
#pragma unroll
  for (int ni = 0; ni < 8; ni++) {
    const int col = ni * 16 + l15;
    bv[ni] = b2[col]; gv[ni] = gamma[col]; btv[ni] = beta[col];
  }
#pragma unroll
  for (int mi = 0; mi < 2; mi++)
#pragma unroll
    for (int r = 0; r < 4; r++) {
      float a = 0.f, bq = 0.f;
#pragma unroll
      for (int ni = 0; ni < 8; ni++) {
        const float v = acc[mi][ni][r] + bv[ni];
        a += v; bq += v * v;
      }
#pragma unroll
      for (int off = 1; off < 16; off <<= 1) {
        a  += __shfl_xor(a, off);
        bq += __shfl_xor(bq, off);
      }
      const float mu = a * (1.0f / 128.0f);
      const float var = fmaxf(bq * (1.0f / 128.0f) - mu * mu, 0.0f);
      const float rs = rsqrtf(var + 1e-5f);
      const int m = m0 + wv * 32 + mi * 16 + quad * 4 + r;
      if (m < M) {
#pragma unroll
        for (int ni = 0; ni < 8; ni++) {
          const int col = ni * 16 + l15;
          const float v = acc[mi][ni][r] + bv[ni];
          const float lnv = (v - mu) * rs * gv[ni] + btv[ni];
          const size_t idx = (size_t)m * DD + col;
          const float nv = lnv + stf[idx];
          stf[idx] = nv;
          stb[idx] = (bf16)nv;
        }
      }
    }
}

// --------------------------- CSR build + aggregate -------------------------
__global__ void zero_kernel(int* __restrict__ p, int n) {
  int i = blockIdx.x * 256 + threadIdx.x;
  if (i < n) p[i] = 0;
}

__global__ void hist_kernel(const int* __restrict__ eidx, int* __restrict__ counts) {
  int e = blockIdx.x * 256 + threadIdx.x;
  if (e < NE) atomicAdd(&counts[eidx[NE + e]], 1);
}

__global__ void scan_kernel(const int* __restrict__ counts, int* __restrict__ offs,
                            int* __restrict__ cursor) {
  __shared__ int sums[1024];
  const int t = threadIdx.x;
  const int base = t * 20;
  int local[20];
  int s = 0;
  for (int i = 0; i < 20; i++) {
    int idx = base + i;
    int c = (idx < NN) ? counts[idx] : 0;
    local[i] = s; s += c;
  }
  sums[t] = s;
  __syncthreads();
  for (int off = 1; off < 1024; off <<= 1) {
    int v = 0;
    if (t >= off) v = sums[t - off];
    __syncthreads();
    if (t >= off) sums[t] += v;
    __syncthreads();
  }
  int excl = (t == 0) ? 0 : sums[t - 1];
  for (int i = 0; i < 20; i++) {
    int idx = base + i;
    if (idx < NN) { offs[idx] = excl + local[i]; cursor[idx] = 0; }
  }
  if (t == 1023) offs[NN] = sums[1023];
}

__global__ void fill_kernel(const int* __restrict__ eidx, const int* __restrict__ offs,
                            int* __restrict__ cursor, int* __restrict__ sorted) {
  int e = blockIdx.x * 256 + threadIdx.x;
  if (e < NE) {
    int n = eidx[NE + e];
    int p = atomicAdd(&cursor[n], 1);
    sorted[offs[n] + p] = e;
  }
}

// wave per node: packed-uint bf16x2 loads, fp32 sums, bf16 out
__global__ void aggregate_kernel(const bf16* __restrict__ eb, const int* __restrict__ offs,
                                 const int* __restrict__ sorted, bf16* __restrict__ aggb) {
  const int node = blockIdx.x * 4 + (threadIdx.x >> 6);
  const int lane = threadIdx.x & 63;
  if (node >= NN) return;
  const int s = offs[node], t = offs[node + 1];
  float a0 = 0.f, a1 = 0.f;
  for (int i = s; i < t; i++) {
    const int e = sorted[i];
    unsigned int v = *(const unsigned int*)(eb + (size_t)e * DD + 2 * lane);
    a0 += bfbits2f(v << 16);            // even col (low half)
    a1 += bfbits2f(v & 0xFFFF0000u);    // odd col (high half)
  }
  bf16 o0 = (bf16)a0, o1 = (bf16)a1;
  unsigned int pack = (unsigned int)(*(unsigned short*)&o0)
                    | ((unsigned int)(*(unsigned short*)&o1) << 16);
  *(unsigned int*)(aggb + (size_t)node * DD + 2 * lane) = pack;
}

// ---------------------------------------------------------------------------
extern "C" void kernel_launch(void* const* d_in, const int* in_sizes, int n_in,
                              void* d_out, int out_size, void* d_ws, size_t ws_size,
                              hipStream_t stream) {
  const void* x_in = d_in[0];
  const void* e_in = d_in[1];
  const void* eW0 = d_in[2];
  const void* eB0 = d_in[3];
  const void* eW1 = d_in[4];
  const void* eB1 = d_in[5];
  const void* eW2 = d_in[6];
  const void* eB2 = d_in[7];
  const void* eG  = d_in[8];
  const void* eBt = d_in[9];
  const void* nW0 = d_in[10];
  const void* nB0 = d_in[11];
  const void* nW1 = d_in[12];
  const void* nB1 = d_in[13];
  const void* nW2 = d_in[14];
  const void* nB2 = d_in[15];
  const void* nG  = d_in[16];
  const void* nBt = d_in[17];
  const int*  eidx = (const int*)d_in[18];

  char* ws = (char*)d_ws;
  size_t off = 0;
  auto alloc = [&](size_t bytes) -> char* {
    char* p = ws + off;
    off = (off + bytes + 255) & ~(size_t)255;
    return p;
  };

  float* xf   = (float*)alloc((size_t)NN * DD * 4);   // fp32 residual states
  float* ef   = (float*)alloc((size_t)NE * DD * 4);
  bf16*  xb   = (bf16*)alloc((size_t)NN * DD * 2);    // bf16 mirrors (GEMM inputs)
  bf16*  eb   = (bf16*)alloc((size_t)NE * DD * 2);
  bf16*  aggb = (bf16*)alloc((size_t)NN * DD * 2);
  bf16*  eW0t = (bf16*)alloc((size_t)NITER * 384 * DD * 2);
  bf16*  eW1t = (bf16*)alloc((size_t)NITER * 128 * DD * 2);
  bf16*  eW2t = (bf16*)alloc((size_t)NITER * 128 * DD * 2);
  bf16*  nW0t = (bf16*)alloc((size_t)NITER * 256 * DD * 2);
  bf16*  nW1t = (bf16*)alloc((size_t)NITER * 128 * DD * 2);
  bf16*  nW2t = (bf16*)alloc((size_t)NITER * 128 * DD * 2);
  const int NB = NITER * DD;
  float* eB0f = (float*)alloc(NB * 4);
  float* eB1f = (float*)alloc(NB * 4);
  float* eB2f = (float*)alloc(NB * 4);
  float* eGf  = (float*)alloc(NB * 4);
  float* eBtf = (float*)alloc(NB * 4);
  float* nB0f = (float*)alloc(NB * 4);
  float* nB1f = (float*)alloc(NB * 4);
  float* nB2f = (float*)alloc(NB * 4);
  float* nGf  = (float*)alloc(NB * 4);
  float* nBtf = (float*)alloc(NB * 4);
  int* counts = (int*)alloc((size_t)NN * 4);
  int* cursor = (int*)alloc((size_t)NN * 4);
  int* offs   = (int*)alloc((size_t)(NN + 1) * 4);
  int* sorted = (int*)alloc((size_t)NE * 4);
  int* flag   = (int*)alloc(4);

  detect_kernel<<<1, 256, 0, stream>>>((const unsigned short*)x_in, 16384, flag);

  in2fb_kernel<<<(NN * DD + 255) / 256, 256, 0, stream>>>(x_in, xf, xb, NN * DD, flag);
  in2fb_kernel<<<(NE * DD + 255) / 256, 256, 0, stream>>>(e_in, ef, eb, NE * DD, flag);
  w2t_kernel<<<(NITER * 384 * DD + 255) / 256, 256, 0, stream>>>(eW0, eW0t, 384, flag);
  w2t_kernel<<<(NITER * 128 * DD + 255) / 256, 256, 0, stream>>>(eW1, eW1t, 128, flag);
  w2t_kernel<<<(NITER * 128 * DD + 255) / 256, 256, 0, stream>>>(eW2, eW2t, 128, flag);
  w2t_kernel<<<(NITER * 256 * DD + 255) / 256, 256, 0, stream>>>(nW0, nW0t, 256, flag);
  w2t_kernel<<<(NITER * 128 * DD + 255) / 256, 256, 0, stream>>>(nW1, nW1t, 128, flag);
  w2t_kernel<<<(NITER * 128 * DD + 255) / 256, 256, 0, stream>>>(nW2, nW2t, 128, flag);
  in2f_kernel<<<(NB + 255) / 256, 256, 0, stream>>>(eB0, eB0f, NB, flag);
  in2f_kernel<<<(NB + 255) / 256, 256, 0, stream>>>(eB1, eB1f, NB, flag);
  in2f_kernel<<<(NB + 255) / 256, 256, 0, stream>>>(eB2, eB2f, NB, flag);
  in2f_kernel<<<(NB + 255) / 256, 256, 0, stream>>>(eG,  eGf,  NB, flag);
  in2f_kernel<<<(NB + 255) / 256, 256, 0, stream>>>(eBt, eBtf, NB, flag);
  in2f_kernel<<<(NB + 255) / 256, 256, 0, stream>>>(nB0, nB0f, NB, flag);
  in2f_kernel<<<(NB + 255) / 256, 256, 0, stream>>>(nB1, nB1f, NB, flag);
  in2f_kernel<<<(NB + 255) / 256, 256, 0, stream>>>(nB2, nB2f, NB, flag);
  in2f_kernel<<<(NB + 255) / 256, 256, 0, stream>>>(nG,  nGf,  NB, flag);
  in2f_kernel<<<(NB + 255) / 256, 256, 0, stream>>>(nBt, nBtf, NB, flag);

  zero_kernel<<<(NN + 255) / 256, 256, 0, stream>>>(counts, NN);
  hist_kernel<<<(NE + 255) / 256, 256, 0, stream>>>(eidx, counts);
  scan_kernel<<<1, 1024, 0, stream>>>(counts, offs, cursor);
  fill_kernel<<<(NE + 255) / 256, 256, 0, stream>>>(eidx, offs, cursor, sorted);

  const int egrid = NE / 128;               // 625
  const int ngrid = (NN + 127) / 128;       // 157

  for (int t = 0; t < NITER; t++) {
    fused_mlp<384, 1><<<egrid, 256, 0, stream>>>(
        xb, eb, eidx,
        eW0t + (size_t)t * 384 * DD, eW1t + (size_t)t * 128 * DD, eW2t + (size_t)t * 128 * DD,
        eB0f + t * DD, eB1f + t * DD, eB2f + t * DD,
        eGf + t * DD, eBtf + t * DD, ef, eb, NE);
    aggregate_kernel<<<(NN + 3) / 4, 256, 0, stream>>>(eb, offs, sorted, aggb);
    fused_mlp<256, 2><<<ngrid, 256, 0, stream>>>(
        xb, aggb, nullptr,
        nW0t + (size_t)t * 256 * DD, nW1t + (size_t)t * 128 * DD, nW2t + (size_t)t * 128 * DD,
        nB0f + t * DD, nB1f + t * DD, nB2f + t * DD,
        nGf + t * DD, nBtf + t * DD, xf, xb, NN);
  }

  outw_kernel<<<((NN + NE) * DD + 255) / 256, 256, 0, stream>>>(xf, ef, d_out, flag);
}

// Round 8
// 1145.126 us; speedup vs baseline: 1.1309x; 1.1309x over previous
//
#include <hip/hip_runtime.h>
#include <hip/hip_bf16.h>

typedef __hip_bfloat16 bf16;
typedef __attribute__((ext_vector_type(8))) short short8;
typedef __attribute__((ext_vector_type(4))) float f32x4;

#define NN 20000
#define NE 80000
#define DD 128
#define NITER 15
#define HSTRIDE 136   // 272 B row stride: 16B-aligned rows, 2-way LDS aliasing (free)

__device__ inline void gload16(const void* g, void* l) {
  __builtin_amdgcn_global_load_lds(
      (const __attribute__((address_space(1))) void*)g,
      (__attribute__((address_space(3))) void*)l, 16, 0, 0);
}

__device__ inline float bfbits2f(unsigned int hi16) {
  union { unsigned int u; float f; } c; c.u = hi16; return c.f;
}

// ---------------------------------------------------------------------------
// dtype auto-detect. flag = 1 -> bf16 ; flag = 0 -> fp32.
// ---------------------------------------------------------------------------
__global__ void detect_kernel(const unsigned short* __restrict__ p, int nhalf,
                              int* __restrict__ flag) {
  __shared__ int cs[256], ct[256];
  const int t = threadIdx.x;
  int sane = 0, tot = 0;
  for (int i = 2 * t; i < nhalf; i += 512) {
    unsigned short v = p[i];
    int e = (v >> 7) & 0xFF;
    tot++;
    if (v == 0 || (e >= 80 && e <= 170)) sane++;
  }
  cs[t] = sane; ct[t] = tot;
  __syncthreads();
  for (int o = 128; o > 0; o >>= 1) {
    if (t < o) { cs[t] += cs[t + o]; ct[t] += ct[t + o]; }
    __syncthreads();
  }
  if (t == 0) *flag = (cs[0] * 10 > ct[0] * 7) ? 1 : 0;
}

// src (bf16 or fp32 per flag) -> bf16
__global__ void in2b_kernel(const void* __restrict__ src, bf16* __restrict__ dst,
                            int n, const int* __restrict__ flag) {
  int i = blockIdx.x * 256 + threadIdx.x;
  if (i < n) {
    float v = (*flag) ? (float)((const bf16*)src)[i] : ((const float*)src)[i];
    dst[i] = (bf16)v;
  }
}

__global__ void in2f_kernel(const void* __restrict__ src, float* __restrict__ dst,
                            int n, const int* __restrict__ flag) {
  int i = blockIdx.x * 256 + threadIdx.x;
  if (i < n) {
    dst[i] = (*flag) ? (float)((const bf16*)src)[i] : ((const float*)src)[i];
  }
}

// W [NITER][K][128] -> Wt [NITER][128][K] bf16
__global__ void w2t_kernel(const void* __restrict__ W, bf16* __restrict__ Wt,
                           int K, const int* __restrict__ flag) {
  int i = blockIdx.x * 256 + threadIdx.x;
  int total = NITER * K * DD;
  if (i < total) {
    float v = (*flag) ? (float)((const bf16*)W)[i] : ((const float*)W)[i];
    int t = i / (K * DD);
    int rem = i - t * K * DD;
    int k = rem >> 7;
    int n = rem & 127;
    Wt[(size_t)t * K * DD + (size_t)n * K + k] = (bf16)v;
  }
}

// bf16 states -> d_out in detected dtype
__global__ void outwb_kernel(const bf16* __restrict__ xb, const bf16* __restrict__ eb,
                             void* __restrict__ out, const int* __restrict__ flag) {
  int i = blockIdx.x * 256 + threadIdx.x;
  const int nx = NN * DD, total = (NN + NE) * DD;
  if (i < total) {
    bf16 v = (i < nx) ? xb[i] : eb[i - nx];
    if (*flag) ((bf16*)out)[i] = v;
    else       ((float*)out)[i] = (float)v;
  }
}

// ---------------------------------------------------------------------------
// Fused 3-layer MLP. TM-row x 128-col tile (TM=128 edge / 64 node), 4
// row-split waves (wave = TM/4 rows x 128 cols). B staged via double-buffered
// global_load_lds (one barrier per 32-K slab); A gathered direct-to-register.
// LayerNorm LDS-free (full row per wave). Residual state is bf16-only: the
// epilogue reads st[idx], adds, writes back (own rows only -> no race).
// AMODE 1: A0 = concat(xb[row[m]], xb[col[m]], eb[m])  (K0=384)
// AMODE 2: A0 = concat(xb[m], aggb[m])                 (K0=256)
// ---------------------------------------------------------------------------
template<int K0, int AMODE, int TM>
__global__ __launch_bounds__(256, 3) void fused_mlp(
    const bf16*  __restrict__ S0b,
    const bf16*  __restrict__ S1b,
    const int*   __restrict__ eidx,
    const bf16*  __restrict__ W0t,   // [128][K0]
    const bf16*  __restrict__ W1t,   // [128][128]
    const bf16*  __restrict__ W2t,   // [128][128]
    const float* __restrict__ b0,
    const float* __restrict__ b1,
    const float* __restrict__ b2,
    const float* __restrict__ gamma,
    const float* __restrict__ beta,
    bf16*        __restrict__ st,    // bf16 residual state (in/out)
    int M)
{
  constexpr int MI = TM / 64;        // acc row-fragments per wave (2 or 1)
  constexpr int WB = TM / 4;         // wave's row band

  __shared__ __align__(16) bf16 Bls[2][128 * 32];   // double-buffered W slab
  __shared__ __align__(16) bf16 Hls[TM * HSTRIDE];  // inter-layer activations

  const int tid  = threadIdx.x;
  const int lane = tid & 63;
  const int wv   = tid >> 6;
  const int l15  = lane & 15, quad = lane >> 4;
  const int m0   = blockIdx.x * TM;

  const int scol = tid >> 2;                  // DMA: weight col 0..63 (+64)
  const int sk8  = (tid & 3) * 8;             // DMA: 8-elem chunk in slab

  int rowm[MI], ir[MI], ic[MI];
#pragma unroll
  for (int mi = 0; mi < MI; mi++) {
    rowm[mi] = min(m0 + wv * WB + mi * 16 + l15, M - 1);
    if (AMODE == 1) { ir[mi] = eidx[rowm[mi]]; ic[mi] = eidx[NE + rowm[mi]]; }
  }

  auto dmaW = [&](const bf16* W, int K, int kk, int buf) {
    gload16(W + (size_t)scol * K + kk + sk8,        &Bls[buf][scol * 32 + sk8]);
    gload16(W + (size_t)(scol + 64) * K + kk + sk8, &Bls[buf][(scol + 64) * 32 + sk8]);
  };
  auto gatherA = [&](int kk, short8 a[MI]) {
    const int ks = (kk & 127) + quad * 8;
#pragma unroll
    for (int mi = 0; mi < MI; mi++) {
      const bf16* base;
      if (AMODE == 1) {
        const int seg = kk >> 7;
        base = (seg == 0) ? S0b + (size_t)ir[mi] * DD
             : (seg == 1) ? S0b + (size_t)ic[mi] * DD
                          : S1b + (size_t)rowm[mi] * DD;
      } else {
        base = (kk >> 7) ? S1b + (size_t)rowm[mi] * DD
                         : S0b + (size_t)rowm[mi] * DD;
      }
      a[mi] = *(const short8*)(base + ks);
    }
  };

  f32x4 acc[MI][8];
  auto zacc = [&]() {
#pragma unroll
    for (int i = 0; i < MI; i++)
#pragma unroll
      for (int j = 0; j < 8; j++) acc[i][j] = (f32x4){0.f, 0.f, 0.f, 0.f};
  };
  auto slabMfmaA = [&](const short8 a[MI], int buf) {
    short8 bfr[8];
#pragma unroll
    for (int ni = 0; ni < 8; ni++)
      bfr[ni] = *(const short8*)&Bls[buf][(ni * 16 + l15) * 32 + quad * 8];
#pragma unroll
    for (int mi = 0; mi < MI; mi++)
#pragma unroll
      for (int ni = 0; ni < 8; ni++)
        acc[mi][ni] = __builtin_amdgcn_mfma_f32_16x16x32_bf16(a[mi], bfr[ni], acc[mi][ni], 0, 0, 0);
  };
  auto slabMfmaH = [&](int kk, int buf) {
    short8 a[MI], bfr[8];
#pragma unroll
    for (int mi = 0; mi < MI; mi++)
      a[mi] = *(const short8*)&Hls[(wv * WB + mi * 16 + l15) * HSTRIDE + kk + quad * 8];
#pragma unroll
    for (int ni = 0; ni < 8; ni++)
      bfr[ni] = *(const short8*)&Bls[buf][(ni * 16 + l15) * 32 + quad * 8];
#pragma unroll
    for (int mi = 0; mi < MI; mi++)
#pragma unroll
      for (int ni = 0; ni < 8; ni++)
        acc[mi][ni] = __builtin_amdgcn_mfma_f32_16x16x32_bf16(a[mi], bfr[ni], acc[mi][ni], 0, 0, 0);
  };
  auto writeH = [&](const float* bias) {
    float bv[8];
#pragma unroll
    for (int ni = 0; ni < 8; ni++) bv[ni] = bias[ni * 16 + l15];
#pragma unroll
    for (int mi = 0; mi < MI; mi++)
#pragma unroll
      for (int r = 0; r < 4; r++) {
        const int row = wv * WB + mi * 16 + quad * 4 + r;
#pragma unroll
        for (int ni = 0; ni < 8; ni++)
          Hls[row * HSTRIDE + ni * 16 + l15] = (bf16)fmaxf(acc[mi][ni][r] + bv[ni], 0.f);
      }
  };

  constexpr int NS1 = K0 / 32;      // phase-1 slabs (12 or 8); even

  // ---------------- Phase 1: H0 = relu(A0 @ W0 + b0) ----------------
  zacc();
  short8 aCur[MI], aNxt[MI];
  dmaW(W0t, K0, 0, 0);
  gatherA(0, aCur);
  __syncthreads();
#pragma unroll
  for (int s = 0; s < NS1; s++) {
    if (s + 1 < NS1) {
      dmaW(W0t, K0, (s + 1) * 32, (s + 1) & 1);
      gatherA((s + 1) * 32, aNxt);
    } else {
      dmaW(W1t, 128, 0, NS1 & 1);
    }
    slabMfmaA(aCur, s & 1);
    __syncthreads();
#pragma unroll
    for (int mi = 0; mi < MI; mi++) aCur[mi] = aNxt[mi];
  }
  writeH(b0);
  __syncthreads();

  // ---------------- Phase 2: H1 = relu(H0 @ W1 + b1) ----------------
  zacc();
#pragma unroll
  for (int s = 0; s < 4; s++) {
    if (s < 3) dmaW(W1t, 128, (s + 1) * 32, (NS1 + s + 1) & 1);
    else       dmaW(W2t, 128, 0,            (NS1 + 4) & 1);
    slabMfmaH(s * 32, (NS1 + s) & 1);
    __syncthreads();
  }
  writeH(b1);
  __syncthreads();

  // ---------------- Phase 3: Y = H1 @ W2 + b2 ; LN ; residual ----------------
  zacc();
#pragma unroll
  for (int s = 0; s < 4; s++) {
    if (s < 3) dmaW(W2t, 128, (s + 1) * 32, (NS1 + 4 + s + 1) & 1);
    slabMfmaH(s * 32, (NS1 + 4 + s) & 1);
    if (s < 3) __syncthreads();
  }

  // LN: full row within wave -> in-lane ni-sum + 16-lane butterfly. No LDS.
  float bv[8], gv[8], btv[8];
#pragma unroll
  for (int ni = 0; ni < 8; ni++) {
    const int col = ni * 16 + l15;
    bv[ni] = b2[col]; gv[ni] = gamma[col]; btv[ni] = beta[col];
  }
#pragma unroll
  for (int mi = 0; mi < MI; mi++)
#pragma unroll
    for (int r = 0; r < 4; r++) {
      float a = 0.f, bq = 0.f;
#pragma unroll
      for (int ni = 0; ni < 8; ni++) {
        const float v = acc[mi][ni][r] + bv[ni];
        a += v; bq += v * v;
      }
#pragma unroll
      for (int off = 1; off < 16; off <<= 1) {
        a  += __shfl_xor(a, off);
        bq += __shfl_xor(bq, off);
      }
      const float mu = a * (1.0f / 128.0f);
      const float var = fmaxf(bq * (1.0f / 128.0f) - mu * mu, 0.0f);
      const float rs = rsqrtf(var + 1e-5f);
      const int m = m0 + wv * WB + mi * 16 + quad * 4 + r;
      if (m < M) {
#pragma unroll
        for (int ni = 0; ni < 8; ni++) {
          const int col = ni * 16 + l15;
          const float v = acc[mi][ni][r] + bv[ni];
          const float lnv = (v - mu) * rs * gv[ni] + btv[ni];
          const size_t idx = (size_t)m * DD + col;
          st[idx] = (bf16)(lnv + (float)st[idx]);
        }
      }
    }
}

// --------------------------- CSR build + aggregate -------------------------
__global__ void zero_kernel(int* __restrict__ p, int n) {
  int i = blockIdx.x * 256 + threadIdx.x;
  if (i < n) p[i] = 0;
}

__global__ void hist_kernel(const int* __restrict__ eidx, int* __restrict__ counts) {
  int e = blockIdx.x * 256 + threadIdx.x;
  if (e < NE) atomicAdd(&counts[eidx[NE + e]], 1);
}

__global__ void scan_kernel(const int* __restrict__ counts, int* __restrict__ offs,
                            int* __restrict__ cursor) {
  __shared__ int sums[1024];
  const int t = threadIdx.x;
  const int base = t * 20;
  int local[20];
  int s = 0;
  for (int i = 0; i < 20; i++) {
    int idx = base + i;
    int c = (idx < NN) ? counts[idx] : 0;
    local[i] = s; s += c;
  }
  sums[t] = s;
  __syncthreads();
  for (int off = 1; off < 1024; off <<= 1) {
    int v = 0;
    if (t >= off) v = sums[t - off];
    __syncthreads();
    if (t >= off) sums[t] += v;
    __syncthreads();
  }
  int excl = (t == 0) ? 0 : sums[t - 1];
  for (int i = 0; i < 20; i++) {
    int idx = base + i;
    if (idx < NN) { offs[idx] = excl + local[i]; cursor[idx] = 0; }
  }
  if (t == 1023) offs[NN] = sums[1023];
}

__global__ void fill_kernel(const int* __restrict__ eidx, const int* __restrict__ offs,
                            int* __restrict__ cursor, int* __restrict__ sorted) {
  int e = blockIdx.x * 256 + threadIdx.x;
  if (e < NE) {
    int n = eidx[NE + e];
    int p = atomicAdd(&cursor[n], 1);
    sorted[offs[n] + p] = e;
  }
}

// wave per node: packed-uint bf16x2 loads, fp32 sums, bf16 out
__global__ void aggregate_kernel(const bf16* __restrict__ eb, const int* __restrict__ offs,
                                 const int* __restrict__ sorted, bf16* __restrict__ aggb) {
  const int node = blockIdx.x * 4 + (threadIdx.x >> 6);
  const int lane = threadIdx.x & 63;
  if (node >= NN) return;
  const int s = offs[node], t = offs[node + 1];
  float a0 = 0.f, a1 = 0.f;
  for (int i = s; i < t; i++) {
    const int e = sorted[i];
    unsigned int v = *(const unsigned int*)(eb + (size_t)e * DD + 2 * lane);
    a0 += bfbits2f(v << 16);
    a1 += bfbits2f(v & 0xFFFF0000u);
  }
  bf16 o0 = (bf16)a0, o1 = (bf16)a1;
  unsigned int pack = (unsigned int)(*(unsigned short*)&o0)
                    | ((unsigned int)(*(unsigned short*)&o1) << 16);
  *(unsigned int*)(aggb + (size_t)node * DD + 2 * lane) = pack;
}

// ---------------------------------------------------------------------------
extern "C" void kernel_launch(void* const* d_in, const int* in_sizes, int n_in,
                              void* d_out, int out_size, void* d_ws, size_t ws_size,
                              hipStream_t stream) {
  const void* x_in = d_in[0];
  const void* e_in = d_in[1];
  const void* eW0 = d_in[2];
  const void* eB0 = d_in[3];
  const void* eW1 = d_in[4];
  const void* eB1 = d_in[5];
  const void* eW2 = d_in[6];
  const void* eB2 = d_in[7];
  const void* eG  = d_in[8];
  const void* eBt = d_in[9];
  const void* nW0 = d_in[10];
  const void* nB0 = d_in[11];
  const void* nW1 = d_in[12];
  const void* nB1 = d_in[13];
  const void* nW2 = d_in[14];
  const void* nB2 = d_in[15];
  const void* nG  = d_in[16];
  const void* nBt = d_in[17];
  const int*  eidx = (const int*)d_in[18];

  char* ws = (char*)d_ws;
  size_t off = 0;
  auto alloc = [&](size_t bytes) -> char* {
    char* p = ws + off;
    off = (off + bytes + 255) & ~(size_t)255;
    return p;
  };

  bf16*  xb   = (bf16*)alloc((size_t)NN * DD * 2);    // bf16 node state
  bf16*  eb   = (bf16*)alloc((size_t)NE * DD * 2);    // bf16 edge state
  bf16*  aggb = (bf16*)alloc((size_t)NN * DD * 2);
  bf16*  eW0t = (bf16*)alloc((size_t)NITER * 384 * DD * 2);
  bf16*  eW1t = (bf16*)alloc((size_t)NITER * 128 * DD * 2);
  bf16*  eW2t = (bf16*)alloc((size_t)NITER * 128 * DD * 2);
  bf16*  nW0t = (bf16*)alloc((size_t)NITER * 256 * DD * 2);
  bf16*  nW1t = (bf16*)alloc((size_t)NITER * 128 * DD * 2);
  bf16*  nW2t = (bf16*)alloc((size_t)NITER * 128 * DD * 2);
  const int NB = NITER * DD;
  float* eB0f = (float*)alloc(NB * 4);
  float* eB1f = (float*)alloc(NB * 4);
  float* eB2f = (float*)alloc(NB * 4);
  float* eGf  = (float*)alloc(NB * 4);
  float* eBtf = (float*)alloc(NB * 4);
  float* nB0f = (float*)alloc(NB * 4);
  float* nB1f = (float*)alloc(NB * 4);
  float* nB2f = (float*)alloc(NB * 4);
  float* nGf  = (float*)alloc(NB * 4);
  float* nBtf = (float*)alloc(NB * 4);
  int* counts = (int*)alloc((size_t)NN * 4);
  int* cursor = (int*)alloc((size_t)NN * 4);
  int* offs   = (int*)alloc((size_t)(NN + 1) * 4);
  int* sorted = (int*)alloc((size_t)NE * 4);
  int* flag   = (int*)alloc(4);

  detect_kernel<<<1, 256, 0, stream>>>((const unsigned short*)x_in, 16384, flag);

  in2b_kernel<<<(NN * DD + 255) / 256, 256, 0, stream>>>(x_in, xb, NN * DD, flag);
  in2b_kernel<<<(NE * DD + 255) / 256, 256, 0, stream>>>(e_in, eb, NE * DD, flag);
  w2t_kernel<<<(NITER * 384 * DD + 255) / 256, 256, 0, stream>>>(eW0, eW0t, 384, flag);
  w2t_kernel<<<(NITER * 128 * DD + 255) / 256, 256, 0, stream>>>(eW1, eW1t, 128, flag);
  w2t_kernel<<<(NITER * 128 * DD + 255) / 256, 256, 0, stream>>>(eW2, eW2t, 128, flag);
  w2t_kernel<<<(NITER * 256 * DD + 255) / 256, 256, 0, stream>>>(nW0, nW0t, 256, flag);
  w2t_kernel<<<(NITER * 128 * DD + 255) / 256, 256, 0, stream>>>(nW1, nW1t, 128, flag);
  w2t_kernel<<<(NITER * 128 * DD + 255) / 256, 256, 0, stream>>>(nW2, nW2t, 128, flag);
  in2f_kernel<<<(NB + 255) / 256, 256, 0, stream>>>(eB0, eB0f, NB, flag);
  in2f_kernel<<<(NB + 255) / 256, 256, 0, stream>>>(eB1, eB1f, NB, flag);
  in2f_kernel<<<(NB + 255) / 256, 256, 0, stream>>>(eB2, eB2f, NB, flag);
  in2f_kernel<<<(NB + 255) / 256, 256, 0, stream>>>(eG,  eGf,  NB, flag);
  in2f_kernel<<<(NB + 255) / 256, 256, 0, stream>>>(eBt, eBtf, NB, flag);
  in2f_kernel<<<(NB + 255) / 256, 256, 0, stream>>>(nB0, nB0f, NB, flag);
  in2f_kernel<<<(NB + 255) / 256, 256, 0, stream>>>(nB1, nB1f, NB, flag);
  in2f_kernel<<<(NB + 255) / 256, 256, 0, stream>>>(nB2, nB2f, NB, flag);
  in2f_kernel<<<(NB + 255) / 256, 256, 0, stream>>>(nG,  nGf,  NB, flag);
  in2f_kernel<<<(NB + 255) / 256, 256, 0, stream>>>(nBt, nBtf, NB, flag);

  zero_kernel<<<(NN + 255) / 256, 256, 0, stream>>>(counts, NN);
  hist_kernel<<<(NE + 255) / 256, 256, 0, stream>>>(eidx, counts);
  scan_kernel<<<1, 1024, 0, stream>>>(counts, offs, cursor);
  fill_kernel<<<(NE + 255) / 256, 256, 0, stream>>>(eidx, offs, cursor, sorted);

  const int egrid = NE / 128;               // 625
  const int ngrid = (NN + 63) / 64;         // 313

  for (int t = 0; t < NITER; t++) {
    fused_mlp<384, 1, 128><<<egrid, 256, 0, stream>>>(
        xb, eb, eidx,
        eW0t + (size_t)t * 384 * DD, eW1t + (size_t)t * 128 * DD, eW2t + (size_t)t * 128 * DD,
        eB0f + t * DD, eB1f + t * DD, eB2f + t * DD,
        eGf + t * DD, eBtf + t * DD, eb, NE);
    aggregate_kernel<<<(NN + 3) / 4, 256, 0, stream>>>(eb, offs, sorted, aggb);
    fused_mlp<256, 2, 64><<<ngrid, 256, 0, stream>>>(
        xb, aggb, nullptr,
        nW0t + (size_t)t * 256 * DD, nW1t + (size_t)t * 128 * DD, nW2t + (size_t)t * 128 * DD,
        nB0f + t * DD, nB1f + t * DD, nB2f + t * DD,
        nGf + t * DD, nBtf + t * DD, xb, NN);
  }

  outwb_kernel<<<((NN + NE) * DD + 255) / 256, 256, 0, stream>>>(xb, eb, d_out, flag);
}